// Round 13
// baseline (124.059 us; speedup 1.0000x reference)
//
#include <hip/hip_runtime.h>
#include <hip/hip_fp16.h>

#define DIV_UP(a,b) (((a)+(b)-1)/(b))

typedef _Float16 half8 __attribute__((ext_vector_type(8)));
typedef float f32x4 __attribute__((ext_vector_type(4)));

// Bucketed CSR build: buckets of 256 destination nodes.
#define BUK_BITS 8
#define BUK_SIZE 256
#define BUK_CAP  6144    // max real records/bucket (mean 4082, +32 sigma)
#define CSR_CAP  8192    // per-bucket csr section (real + row-pad <= 6144+1792)
#define MAXBUK   256     // nbuk = ceil(50000/256) = 196
#define NBLK_BUCKET 256
#define CHUNK_MAX 3136   // >= ceil(800000/256)

// LDS swizzle for the gemmf strip buffer (halves)
#define SWZ(row, colh) ((colh) ^ (((row) & 7) << 3))

// NOTE: CSR entries are ushort source ids; sentinel = n (50000 < 65536) points
// to an all-zero row so every CSR row is padded to a multiple of 8.

__device__ __forceinline__ int edge_at(const void* ei, int mode64, int idx) {
  if (mode64) return (int)((const long long*)ei)[idx];
  return ((const int*)ei)[idx];
}

// Small init kernel (NO hipMemsetAsync — the runtime's 1KB fill kernel costs
// ~43us in graph replay, measured R12): zero bcur + transpose W1/W2 to fp16.
__global__ __launch_bounds__(256) void k_init(int* __restrict__ bcur,
                                              const float* __restrict__ W1,
                                              const float* __restrict__ W2,
                                              _Float16* __restrict__ Wt1,
                                              _Float16* __restrict__ Wt2) {
  int i = blockIdx.x * 256 + threadIdx.x;    // 97 blocks: 0 .. 24831
  if (i < MAXBUK) bcur[i] = 0;
  if (i < 128 * 128) {
    int nc = i >> 7, k = i & 127;
    Wt1[i] = (k < 100) ? (_Float16)W1[k * 128 + nc] : (_Float16)0.f;
  } else if (i < 128 * 128 + 64 * 128) {
    int j = i - 128 * 128;
    int nc = j >> 7, k = j & 127;
    Wt2[j] = (_Float16)W2[k * 64 + nc];
  }
}

// ---------------------------------------------------------------------------
// Phase 1: bucket edges by destination range. rec = (c<<16) | r.
// mode (int64 vs int32) detected per-block; bcur zero-init (relative counts).
// ---------------------------------------------------------------------------
__global__ __launch_bounds__(256) void k_bucket(const void* __restrict__ ei,
                                                int* __restrict__ bcur,
                                                unsigned int* __restrict__ recs,
                                                int E, int nbuk) {
  __shared__ unsigned int lrec[CHUNK_MAX];
  __shared__ unsigned int sorted[CHUNK_MAX];
  __shared__ int hist[MAXBUK], lofs[MAXBUK], gbase[MAXBUK], cur[MAXBUK];
  __shared__ int smode;

  if (threadIdx.x < 64) {                    // wave 0: detect int64 vs int32
    int v = ((const int*)ei)[2 * threadIdx.x + 1];
    unsigned long long b = __ballot(v == 0);
    if (threadIdx.x == 0) smode = (b == ~0ull) ? 1 : 0;
  }
  for (int i = threadIdx.x; i < nbuk; i += 256) hist[i] = 0;
  __syncthreads();
  const int m = smode;

  const int chunk = DIV_UP(E, gridDim.x);
  const int e0 = blockIdx.x * chunk;
  const int cnt = min(E, e0 + chunk) - e0;
  if (cnt <= 0) return;

  for (int i = threadIdx.x; i < cnt; i += 256) {
    int r = edge_at(ei, m, e0 + i);
    int c = edge_at(ei, m, E + e0 + i);
    unsigned int rec = ((unsigned)c << 16) | (unsigned)r;
    lrec[i] = rec;
    atomicAdd(&hist[c >> BUK_BITS], 1);
  }
  __syncthreads();

  if (threadIdx.x == 0) {            // serial exclusive scan over <=196 buckets
    int run = 0;
    for (int b = 0; b < nbuk; ++b) { lofs[b] = run; run += hist[b]; }
  }
  __syncthreads();
  for (int b = threadIdx.x; b < nbuk; b += 256) {
    gbase[b] = b * BUK_CAP + atomicAdd(&bcur[b], hist[b]);
    cur[b] = lofs[b];
  }
  __syncthreads();

  for (int i = threadIdx.x; i < cnt; i += 256) {
    unsigned int rec = lrec[i];
    int b = rec >> (16 + BUK_BITS);
    int p = atomicAdd(&cur[b], 1);
    sorted[p] = rec;
  }
  __syncthreads();

  for (int i = threadIdx.x; i < cnt; i += 256) {
    unsigned int rec = sorted[i];
    int b = rec >> (16 + BUK_BITS);
    recs[gbase[b] + i - lofs[b]] = rec;
  }
}

// ---------------------------------------------------------------------------
// Phase 2 (bdeg + csrfill + convx fused): per bucket of 256 dest nodes —
// hist -> dinv + rowinfo{beg,plen}; CSR section in LDS (pads = sentinel n);
// converts the bucket's x rows to fp16 xh (row = 32 uint2, cols 100..127 zero).
// Block 0 zeroes the sentinel rows xh[n], thh[n].
// ---------------------------------------------------------------------------
__global__ __launch_bounds__(256) void k_bdeg_fill(const int* __restrict__ bcur,
                                                   const unsigned int* __restrict__ recs,
                                                   const float4* __restrict__ x4,
                                                   float* __restrict__ dinv,
                                                   int2* __restrict__ rowinfo,
                                                   unsigned short* __restrict__ csr,
                                                   uint2* __restrict__ xh4,
                                                   uint2* __restrict__ thh2,
                                                   int n) {
  __shared__ int h[BUK_SIZE];
  __shared__ int psum[BUK_SIZE];
  __shared__ int curs[BUK_SIZE];
  __shared__ unsigned short lcsr[CSR_CAP];

  const int b = blockIdx.x, tid = threadIdx.x;
  const int base = b * BUK_CAP;
  const int cnt = bcur[b];                  // relative count (bcur zero-init)
  const int n0 = b << BUK_BITS;
  const int nn = min(BUK_SIZE, n - n0);

  h[tid] = 0;
  __syncthreads();
  for (int i = tid; i < cnt; i += 256)
    atomicAdd(&h[(int)(recs[base + i] >> 16) - n0], 1);
  __syncthreads();

  const int deg = h[tid];
  const int plen = (deg + 7) & ~7;          // row padded to multiple of 8
  psum[tid] = plen;
  __syncthreads();
#pragma unroll
  for (int off2 = 1; off2 < 256; off2 <<= 1) {
    int v = (tid >= off2) ? psum[tid - off2] : 0;
    __syncthreads();
    psum[tid] += v;
    __syncthreads();
  }
  const int excl = psum[tid] - plen;
  const int ptot = psum[255];

  if (tid < nn) {
    rowinfo[n0 + tid] = make_int2(b * CSR_CAP + excl, plen);
    dinv[n0 + tid] = rsqrtf((float)deg + 1.0f);   // +1 = self loop
    curs[tid] = excl;
  }
  for (int i = tid; i < ptot; i += 256) lcsr[i] = (unsigned short)n;  // sentinel pads
  __syncthreads();

  for (int i = tid; i < cnt; i += 256) {
    unsigned int rec = recs[base + i];
    int cl = (int)(rec >> 16) - n0;
    int p = atomicAdd(&curs[cl], 1);
    lcsr[p] = (unsigned short)(rec & 0xFFFFu);
  }
  __syncthreads();
  for (int i = tid; i < ptot; i += 256) csr[b * CSR_CAP + i] = lcsr[i];

  // ---- convx for this bucket's nodes (dinv from LDS hist) ----
  for (int i = tid; i < nn * 32; i += 256) {
    int nl = i >> 5, lane = i & 31;
    int node = n0 + nl;
    uint2 val = make_uint2(0u, 0u);
    if (lane < 25) {
      float d = rsqrtf((float)h[nl] + 1.0f);
      float4 v = x4[node * 25 + lane];
      union { uint2 u; __half2 hh[2]; } p;
      p.hh[0] = __halves2half2(__float2half_rn(d * v.x), __float2half_rn(d * v.y));
      p.hh[1] = __halves2half2(__float2half_rn(d * v.z), __float2half_rn(d * v.w));
      val = p.u;
    }
    xh4[(node << 5) + lane] = val;
  }
  if (b == 0) {
    if (tid < 32) xh4[(n << 5) + tid] = make_uint2(0u, 0u);
    else if (tid < 48) thh2[(n << 4) + (tid - 32)] = make_uint2(0u, 0u);
  }
}

// ---------------------------------------------------------------------------
__device__ __forceinline__ float4 h4_to_f4(uint2 u) {
  union { uint2 u; __half2 h[2]; } p; p.u = u;
  float2 a = __half22float2(p.h[0]);
  float2 b = __half22float2(p.h[1]);
  return make_float4(a.x, a.y, b.x, b.y);
}
__device__ __forceinline__ void acc_add(float4& acc, float4 a) {
  acc.x += a.x; acc.y += a.y; acc.z += a.z; acc.w += a.w;
}

// Layer-1 pull (R7 body): 25 lanes x uint2 per node, 10 nodes/block.
__global__ __launch_bounds__(256) void k_pull1(const int2* __restrict__ rowinfo,
                                               const unsigned short* __restrict__ csr,
                                               const uint2* __restrict__ xh4,
                                               const float* __restrict__ dinv,
                                               uint2* __restrict__ aggh4, int n) {
  int g = threadIdx.x / 25;
  int lane = threadIdx.x - g * 25;
  if (g >= 10) return;
  int node = blockIdx.x * 10 + g;
  if (node >= n) return;

  float4 acc = h4_to_f4(xh4[(node << 5) + lane]);   // self term
  int2 ri = rowinfo[node];
  int beg = ri.x, end = ri.x + ri.y;
  for (int j = beg; j < end; j += 8) {
    uint4 cw = *(const uint4*)&csr[j];
    int r0 = cw.x & 0xFFFF, r1 = cw.x >> 16;
    int r2 = cw.y & 0xFFFF, r3 = cw.y >> 16;
    int r4 = cw.z & 0xFFFF, r5 = cw.z >> 16;
    int r6 = cw.w & 0xFFFF, r7 = cw.w >> 16;
    float4 t0 = h4_to_f4(xh4[(r0 << 5) + lane]);
    float4 t1 = h4_to_f4(xh4[(r1 << 5) + lane]);
    float4 t2 = h4_to_f4(xh4[(r2 << 5) + lane]);
    float4 t3 = h4_to_f4(xh4[(r3 << 5) + lane]);
    float4 t4 = h4_to_f4(xh4[(r4 << 5) + lane]);
    float4 t5 = h4_to_f4(xh4[(r5 << 5) + lane]);
    float4 t6 = h4_to_f4(xh4[(r6 << 5) + lane]);
    float4 t7 = h4_to_f4(xh4[(r7 << 5) + lane]);
    acc_add(acc, t0); acc_add(acc, t1); acc_add(acc, t2); acc_add(acc, t3);
    acc_add(acc, t4); acc_add(acc, t5); acc_add(acc, t6); acc_add(acc, t7);
  }
  float d = dinv[node];
  union { uint2 u; __half2 h[2]; } p;
  p.h[0] = __halves2half2(__float2half_rn(d * acc.x), __float2half_rn(d * acc.y));
  p.h[1] = __halves2half2(__float2half_rn(d * acc.z), __float2half_rn(d * acc.w));
  aggh4[(node << 5) + lane] = p.u;
  if (lane < 7) aggh4[(node << 5) + 25 + lane] = make_uint2(0u, 0u);  // K-pad
}

// Layer-2 pull (R7 body): 8 lanes x uint4 per node, 32 nodes/block.
__global__ __launch_bounds__(256) void k_pull2(const int2* __restrict__ rowinfo,
                                               const unsigned short* __restrict__ csr,
                                               const uint4* __restrict__ th4,
                                               const float* __restrict__ dinv,
                                               const float4* __restrict__ b2_4,
                                               float4* __restrict__ out4, int n) {
  int g = threadIdx.x >> 3;
  int lane = threadIdx.x & 7;
  int node = blockIdx.x * 32 + g;
  if (node >= n) return;

  uint4 sv = th4[(node << 3) + lane];
  float4 acc0 = h4_to_f4(make_uint2(sv.x, sv.y));
  float4 acc1 = h4_to_f4(make_uint2(sv.z, sv.w));

  int2 ri = rowinfo[node];
  int beg = ri.x, end = ri.x + ri.y;
  for (int j = beg; j < end; j += 8) {
    uint4 cw = *(const uint4*)&csr[j];
    int r0 = cw.x & 0xFFFF, r1 = cw.x >> 16;
    int r2 = cw.y & 0xFFFF, r3 = cw.y >> 16;
    int r4 = cw.z & 0xFFFF, r5 = cw.z >> 16;
    int r6 = cw.w & 0xFFFF, r7 = cw.w >> 16;
    uint4 u0 = th4[(r0 << 3) + lane];
    uint4 u1 = th4[(r1 << 3) + lane];
    uint4 u2 = th4[(r2 << 3) + lane];
    uint4 u3 = th4[(r3 << 3) + lane];
    uint4 u4 = th4[(r4 << 3) + lane];
    uint4 u5 = th4[(r5 << 3) + lane];
    uint4 u6 = th4[(r6 << 3) + lane];
    uint4 u7 = th4[(r7 << 3) + lane];
    acc_add(acc0, h4_to_f4(make_uint2(u0.x, u0.y)));
    acc_add(acc1, h4_to_f4(make_uint2(u0.z, u0.w)));
    acc_add(acc0, h4_to_f4(make_uint2(u1.x, u1.y)));
    acc_add(acc1, h4_to_f4(make_uint2(u1.z, u1.w)));
    acc_add(acc0, h4_to_f4(make_uint2(u2.x, u2.y)));
    acc_add(acc1, h4_to_f4(make_uint2(u2.z, u2.w)));
    acc_add(acc0, h4_to_f4(make_uint2(u3.x, u3.y)));
    acc_add(acc1, h4_to_f4(make_uint2(u3.z, u3.w)));
    acc_add(acc0, h4_to_f4(make_uint2(u4.x, u4.y)));
    acc_add(acc1, h4_to_f4(make_uint2(u4.z, u4.w)));
    acc_add(acc0, h4_to_f4(make_uint2(u5.x, u5.y)));
    acc_add(acc1, h4_to_f4(make_uint2(u5.z, u5.w)));
    acc_add(acc0, h4_to_f4(make_uint2(u6.x, u6.y)));
    acc_add(acc1, h4_to_f4(make_uint2(u6.z, u6.w)));
    acc_add(acc0, h4_to_f4(make_uint2(u7.x, u7.y)));
    acc_add(acc1, h4_to_f4(make_uint2(u7.z, u7.w)));
  }
  float d = dinv[node];
  float4 bb0 = b2_4[lane * 2], bb1 = b2_4[lane * 2 + 1];
  out4[(node << 4) + lane * 2]     = make_float4(d * acc0.x + bb0.x, d * acc0.y + bb0.y,
                                                 d * acc0.z + bb0.z, d * acc0.w + bb0.w);
  out4[(node << 4) + lane * 2 + 1] = make_float4(d * acc1.x + bb1.x, d * acc1.y + bb1.y,
                                                 d * acc1.z + bb1.z, d * acc1.w + bb1.w);
}

// ---------------------------------------------------------------------------
// Fused MFMA GEMM: per 16-row strip, h1 = relu(aggh@W1+b1) (swizzled LDS),
// thh = dinv*(h1@W2).
// ---------------------------------------------------------------------------
__global__ __launch_bounds__(256, 2) void k_gemmf(const _Float16* __restrict__ A,
                                                  const _Float16* __restrict__ Wt1,
                                                  const float* __restrict__ b1,
                                                  const _Float16* __restrict__ Wt2,
                                                  const float* __restrict__ dinv,
                                                  _Float16* __restrict__ thh, int n) {
  __shared__ __align__(16) _Float16 lds[4][16 * 128];
  const int wid = threadIdx.x >> 6;
  const int lane = threadIdx.x & 63;
  const int lr = lane & 15;
  const int lk = lane >> 4;
  _Float16* myl = lds[wid];

  half8 B1[8][4];
#pragma unroll
  for (int nt = 0; nt < 8; ++nt)
#pragma unroll
    for (int ks = 0; ks < 4; ++ks)
      B1[nt][ks] = *(const half8*)&Wt1[(nt * 16 + lr) * 128 + ks * 32 + lk * 8];
  float bs[8];
#pragma unroll
  for (int nt = 0; nt < 8; ++nt) bs[nt] = b1[nt * 16 + lr];

  const int nstrips = (n + 15) >> 4;
  for (int s = blockIdx.x * 4 + wid; s < nstrips; s += gridDim.x * 4) {
    const int arow = s * 16 + lr;
    half8 a[4];
#pragma unroll
    for (int ks = 0; ks < 4; ++ks)
      a[ks] = (arow < n) ? *(const half8*)&A[(size_t)arow * 128 + ks * 32 + lk * 8]
                         : half8{0, 0, 0, 0, 0, 0, 0, 0};
    f32x4 acc[8];
#pragma unroll
    for (int nt = 0; nt < 8; ++nt) acc[nt] = f32x4{0.f, 0.f, 0.f, 0.f};
#pragma unroll
    for (int ks = 0; ks < 4; ++ks)
#pragma unroll
      for (int nt = 0; nt < 8; ++nt)
        acc[nt] = __builtin_amdgcn_mfma_f32_16x16x32_f16(a[ks], B1[nt][ks], acc[nt], 0, 0, 0);

#pragma unroll
    for (int r = 0; r < 4; ++r) {
      int row = lk * 4 + r;
#pragma unroll
      for (int nt = 0; nt < 8; ++nt)
        myl[row * 128 + SWZ(row, nt * 16 + lr)] =
            (_Float16)fmaxf(acc[nt][r] + bs[nt], 0.f);
    }

    half8 B2[4][4];
#pragma unroll
    for (int nt = 0; nt < 4; ++nt)
#pragma unroll
      for (int ks = 0; ks < 4; ++ks)
        B2[nt][ks] = *(const half8*)&Wt2[(nt * 16 + lr) * 128 + ks * 32 + lk * 8];

    half8 a2[4];
#pragma unroll
    for (int ks = 0; ks < 4; ++ks)
      a2[ks] = *(const half8*)&myl[lr * 128 + SWZ(lr, ks * 32 + lk * 8)];

    f32x4 acc2[4];
#pragma unroll
    for (int nt = 0; nt < 4; ++nt) acc2[nt] = f32x4{0.f, 0.f, 0.f, 0.f};
#pragma unroll
    for (int ks = 0; ks < 4; ++ks)
#pragma unroll
      for (int nt = 0; nt < 4; ++nt)
        acc2[nt] = __builtin_amdgcn_mfma_f32_16x16x32_f16(a2[ks], B2[nt][ks], acc2[nt], 0, 0, 0);

    const int rb = s * 16 + lk * 4;
    float sc[4];
    if (rb + 3 < n) {
      const float4 dv = *(const float4*)&dinv[rb];
      sc[0] = dv.x; sc[1] = dv.y; sc[2] = dv.z; sc[3] = dv.w;
    } else {
#pragma unroll
      for (int r = 0; r < 4; ++r) sc[r] = (rb + r < n) ? dinv[rb + r] : 0.f;
    }
#pragma unroll
    for (int r = 0; r < 4; ++r) {
      const int orow = rb + r;
      if (orow < n) {
#pragma unroll
        for (int nt = 0; nt < 4; ++nt)
          thh[(size_t)orow * 64 + nt * 16 + lr] = (_Float16)(acc2[nt][r] * sc[r]);
      }
    }
  }
}

// ---------------------------------------------------------------------------
extern "C" void kernel_launch(void* const* d_in, const int* in_sizes, int n_in,
                              void* d_out, int out_size, void* d_ws, size_t ws_size,
                              hipStream_t stream) {
  const float* x  = (const float*)d_in[0];
  const void*  ei = d_in[1];
  const float* W1 = (const float*)d_in[2];
  const float* b1 = (const float*)d_in[3];
  const float* W2 = (const float*)d_in[4];
  const float* b2 = (const float*)d_in[5];
  float* out = (float*)d_out;

  const int n = in_sizes[0] / 100;   // 50000 (multiple of 16; n < 65536)
  const int E = in_sizes[1] / 2;     // 800000
  const int nbuk = DIV_UP(n, BUK_SIZE);  // 196

  // byte allocator, 16B-aligned
  char* ws = (char*)d_ws;
  size_t off = 0;
  auto alloc = [&](size_t bytes) { void* p = ws + off; off += (bytes + 15) & ~15ull; return p; };
  int*            bcur     = (int*)   alloc(MAXBUK * 4);
  float*          dinv     = (float*) alloc((size_t)n * 4);
  int2*           rowinfo  = (int2*)  alloc((size_t)n * 8);
  unsigned int*   recs     = (unsigned int*)alloc((size_t)nbuk * BUK_CAP * 4);
  unsigned short* csr      = (unsigned short*)alloc((size_t)nbuk * CSR_CAP * 2);
  _Float16*       xh       = (_Float16*)alloc((size_t)(n + 1) * 128 * 2);  // + zero row
  _Float16*       aggh     = (_Float16*)alloc((size_t)n * 128 * 2);        // K-padded
  _Float16*       thh      = (_Float16*)alloc((size_t)(n + 1) * 64 * 2);   // + zero row
  _Float16*       Wt1h     = (_Float16*)alloc(128 * 128 * 2);
  _Float16*       Wt2h     = (_Float16*)alloc(64 * 128 * 2);

  k_init<<<97, 256, 0, stream>>>(bcur, W1, W2, Wt1h, Wt2h);
  k_bucket<<<NBLK_BUCKET, 256, 0, stream>>>(ei, bcur, recs, E, nbuk);
  k_bdeg_fill<<<nbuk, 256, 0, stream>>>(bcur, recs, (const float4*)x, dinv,
                                        rowinfo, csr, (uint2*)xh, (uint2*)thh, n);

  k_pull1<<<DIV_UP(n, 10), 256, 0, stream>>>(rowinfo, csr, (const uint2*)xh, dinv,
                                             (uint2*)aggh, n);
  const int nstrips = DIV_UP(n, 16);
  k_gemmf<<<DIV_UP(nstrips, 8), 256, 0, stream>>>(aggh, Wt1h, b1, Wt2h, dinv, thh, n);
  k_pull2<<<DIV_UP(n, 32), 256, 0, stream>>>(rowinfo, csr, (const uint4*)thh, dinv,
                                             (const float4*)b2, (float4*)out, n);
}

// Round 14
// 118.411 us; speedup vs baseline: 1.0477x; 1.0477x over previous
//
#include <hip/hip_runtime.h>
#include <hip/hip_fp16.h>

#define DIV_UP(a,b) (((a)+(b)-1)/(b))

typedef _Float16 half8 __attribute__((ext_vector_type(8)));
typedef float f32x4 __attribute__((ext_vector_type(4)));

// Bucketed CSR build: buckets of 256 destination nodes.
#define BUK_BITS 8
#define BUK_SIZE 256
#define BUK_CAP  6144    // max real records/bucket (mean 4082, +32 sigma)
#define CSR_CAP  8192    // per-bucket csr section (real + row-pad <= 6144+1792)
#define MAXBUK   256     // nbuk = ceil(50000/256) = 196
#define NBLK_BUCKET 256
#define CHUNK_MAX 3136   // >= ceil(800000/256)

// LDS swizzle for the gemmf strip buffer (halves)
#define SWZ(row, colh) ((colh) ^ (((row) & 7) << 3))

// NOTE: CSR entries are ushort source ids; sentinel = n (50000 < 65536) points
// to an all-zero row so every CSR row is padded to a multiple of 8.

__device__ __forceinline__ int edge_at(const void* ei, int mode64, int idx) {
  if (mode64) return (int)((const long long*)ei)[idx];
  return ((const int*)ei)[idx];
}

// Zero bcur + transpose W1/W2 to fp16 (no hipMemsetAsync — R12 showed the
// runtime's tiny fill kernel is pathologically slow in graph replay).
__global__ __launch_bounds__(256) void k_init(int* __restrict__ bcur,
                                              const float* __restrict__ W1,
                                              const float* __restrict__ W2,
                                              _Float16* __restrict__ Wt1,
                                              _Float16* __restrict__ Wt2) {
  int i = blockIdx.x * 256 + threadIdx.x;    // 97 blocks: 0 .. 24831
  if (i < MAXBUK) bcur[i] = 0;
  if (i < 128 * 128) {
    int nc = i >> 7, k = i & 127;
    Wt1[i] = (k < 100) ? (_Float16)W1[k * 128 + nc] : (_Float16)0.f;
  } else if (i < 128 * 128 + 64 * 128) {
    int j = i - 128 * 128;
    int nc = j >> 7, k = j & 127;
    Wt2[j] = (_Float16)W2[k * 64 + nc];
  }
}

// ---------------------------------------------------------------------------
// Phase 1: bucket edges by destination range. rec = (c<<16) | r.
// ---------------------------------------------------------------------------
__global__ __launch_bounds__(256) void k_bucket(const void* __restrict__ ei,
                                                int* __restrict__ bcur,
                                                unsigned int* __restrict__ recs,
                                                int E, int nbuk) {
  __shared__ unsigned int lrec[CHUNK_MAX];
  __shared__ unsigned int sorted[CHUNK_MAX];
  __shared__ int hist[MAXBUK], lofs[MAXBUK], gbase[MAXBUK], cur[MAXBUK];
  __shared__ int smode;

  if (threadIdx.x < 64) {                    // wave 0: detect int64 vs int32
    int v = ((const int*)ei)[2 * threadIdx.x + 1];
    unsigned long long b = __ballot(v == 0);
    if (threadIdx.x == 0) smode = (b == ~0ull) ? 1 : 0;
  }
  for (int i = threadIdx.x; i < nbuk; i += 256) hist[i] = 0;
  __syncthreads();
  const int m = smode;

  const int chunk = DIV_UP(E, gridDim.x);
  const int e0 = blockIdx.x * chunk;
  const int cnt = min(E, e0 + chunk) - e0;
  if (cnt <= 0) return;

  for (int i = threadIdx.x; i < cnt; i += 256) {
    int r = edge_at(ei, m, e0 + i);
    int c = edge_at(ei, m, E + e0 + i);
    unsigned int rec = ((unsigned)c << 16) | (unsigned)r;
    lrec[i] = rec;
    atomicAdd(&hist[c >> BUK_BITS], 1);
  }
  __syncthreads();

  if (threadIdx.x == 0) {            // serial exclusive scan over <=196 buckets
    int run = 0;
    for (int b = 0; b < nbuk; ++b) { lofs[b] = run; run += hist[b]; }
  }
  __syncthreads();
  for (int b = threadIdx.x; b < nbuk; b += 256) {
    gbase[b] = b * BUK_CAP + atomicAdd(&bcur[b], hist[b]);
    cur[b] = lofs[b];
  }
  __syncthreads();

  for (int i = threadIdx.x; i < cnt; i += 256) {
    unsigned int rec = lrec[i];
    int b = rec >> (16 + BUK_BITS);
    int p = atomicAdd(&cur[b], 1);
    sorted[p] = rec;
  }
  __syncthreads();

  for (int i = threadIdx.x; i < cnt; i += 256) {
    unsigned int rec = sorted[i];
    int b = rec >> (16 + BUK_BITS);
    recs[gbase[b] + i - lofs[b]] = rec;
  }
}

// ---------------------------------------------------------------------------
// Phase 2: per bucket of 256 dest nodes — hist -> dinv + rowinfo{beg,plen};
// CSR section in LDS (pads = sentinel n), streamed out coalesced.
// (convx un-fused: a 196-block kernel under-utilizes the machine for the
//  33MB x-conversion — measured ~5us regression R12/R13 vs R7.)
// ---------------------------------------------------------------------------
__global__ __launch_bounds__(256) void k_bdeg_fill(const int* __restrict__ bcur,
                                                   const unsigned int* __restrict__ recs,
                                                   float* __restrict__ dinv,
                                                   int2* __restrict__ rowinfo,
                                                   unsigned short* __restrict__ csr,
                                                   int n) {
  __shared__ int h[BUK_SIZE];
  __shared__ int psum[BUK_SIZE];
  __shared__ int curs[BUK_SIZE];
  __shared__ unsigned short lcsr[CSR_CAP];

  const int b = blockIdx.x, tid = threadIdx.x;
  const int base = b * BUK_CAP;
  const int cnt = bcur[b];                  // relative count (bcur zero-init)
  const int n0 = b << BUK_BITS;
  const int nn = min(BUK_SIZE, n - n0);

  h[tid] = 0;
  __syncthreads();
  for (int i = tid; i < cnt; i += 256)
    atomicAdd(&h[(int)(recs[base + i] >> 16) - n0], 1);
  __syncthreads();

  const int deg = h[tid];
  const int plen = (deg + 7) & ~7;          // row padded to multiple of 8
  psum[tid] = plen;
  __syncthreads();
#pragma unroll
  for (int off2 = 1; off2 < 256; off2 <<= 1) {
    int v = (tid >= off2) ? psum[tid - off2] : 0;
    __syncthreads();
    psum[tid] += v;
    __syncthreads();
  }
  const int excl = psum[tid] - plen;
  const int ptot = psum[255];

  if (tid < nn) {
    rowinfo[n0 + tid] = make_int2(b * CSR_CAP + excl, plen);
    dinv[n0 + tid] = rsqrtf((float)deg + 1.0f);   // +1 = self loop
    curs[tid] = excl;
  }
  for (int i = tid; i < ptot; i += 256) lcsr[i] = (unsigned short)n;  // sentinel pads
  __syncthreads();

  for (int i = tid; i < cnt; i += 256) {
    unsigned int rec = recs[base + i];
    int cl = (int)(rec >> 16) - n0;
    int p = atomicAdd(&curs[cl], 1);
    lcsr[p] = (unsigned short)(rec & 0xFFFFu);
  }
  __syncthreads();
  for (int i = tid; i < ptot; i += 256) csr[b * CSR_CAP + i] = lcsr[i];
}

// xh[node][0..99] = fp16(dinv[node]*x[node][*]), row = 32 uint2 (256B), cols
// 100..127 zero. Sentinel row n fully zero; also zeroes thh sentinel row.
__global__ __launch_bounds__(256) void k_convx(const float4* __restrict__ x4,
                                               const float* __restrict__ dinv,
                                               uint2* __restrict__ xh4,
                                               uint2* __restrict__ thh2,
                                               int n, int total) {
  int i = blockIdx.x * 256 + threadIdx.x;
  if (i < total) {                            // total = (n+1)*32
    int node = i >> 5;
    int lane = i & 31;
    uint2 val = make_uint2(0u, 0u);
    if (node < n && lane < 25) {
      float d = dinv[node];
      float4 v = x4[node * 25 + lane];
      union { uint2 u; __half2 hh[2]; } p;
      p.hh[0] = __halves2half2(__float2half_rn(d * v.x), __float2half_rn(d * v.y));
      p.hh[1] = __halves2half2(__float2half_rn(d * v.z), __float2half_rn(d * v.w));
      val = p.u;
    }
    xh4[i] = val;
  } else {
    int s = i - total;
    if (s < 16) thh2[(n << 4) + s] = make_uint2(0u, 0u);   // thh sentinel row
  }
}

// ---------------------------------------------------------------------------
__device__ __forceinline__ float4 h4_to_f4(uint2 u) {
  union { uint2 u; __half2 h[2]; } p; p.u = u;
  float2 a = __half22float2(p.h[0]);
  float2 b = __half22float2(p.h[1]);
  return make_float4(a.x, a.y, b.x, b.y);
}
__device__ __forceinline__ void acc_add(float4& acc, float4 a) {
  acc.x += a.x; acc.y += a.y; acc.z += a.z; acc.w += a.w;
}

// Layer-1 pull: 25 lanes x uint2 per node, 10 nodes/block. 16-edge unroll
// (two uint4 CSR words) doubles outstanding gathers per wave: in-flight
// bytes were ~= BW x latency (2.5MB) at 8-deep -> latency-limited, not BW.
__global__ __launch_bounds__(256) void k_pull1(const int2* __restrict__ rowinfo,
                                               const unsigned short* __restrict__ csr,
                                               const uint2* __restrict__ xh4,
                                               const float* __restrict__ dinv,
                                               uint2* __restrict__ aggh4, int n) {
  int g = threadIdx.x / 25;
  int lane = threadIdx.x - g * 25;
  if (g >= 10) return;
  int node = blockIdx.x * 10 + g;
  if (node >= n) return;

  float4 acc = h4_to_f4(xh4[(node << 5) + lane]);   // self term
  int2 ri = rowinfo[node];
  int beg = ri.x, end = ri.x + ri.y;
  int j = beg;
  for (; j + 16 <= end; j += 16) {
    uint4 cw0 = *(const uint4*)&csr[j];
    uint4 cw1 = *(const uint4*)&csr[j + 8];
    int r0 = cw0.x & 0xFFFF, r1 = cw0.x >> 16;
    int r2 = cw0.y & 0xFFFF, r3 = cw0.y >> 16;
    int r4 = cw0.z & 0xFFFF, r5 = cw0.z >> 16;
    int r6 = cw0.w & 0xFFFF, r7 = cw0.w >> 16;
    int r8 = cw1.x & 0xFFFF, r9 = cw1.x >> 16;
    int rA = cw1.y & 0xFFFF, rB = cw1.y >> 16;
    int rC = cw1.z & 0xFFFF, rD = cw1.z >> 16;
    int rE = cw1.w & 0xFFFF, rF = cw1.w >> 16;
    float4 t0 = h4_to_f4(xh4[(r0 << 5) + lane]);
    float4 t1 = h4_to_f4(xh4[(r1 << 5) + lane]);
    float4 t2 = h4_to_f4(xh4[(r2 << 5) + lane]);
    float4 t3 = h4_to_f4(xh4[(r3 << 5) + lane]);
    float4 t4 = h4_to_f4(xh4[(r4 << 5) + lane]);
    float4 t5 = h4_to_f4(xh4[(r5 << 5) + lane]);
    float4 t6 = h4_to_f4(xh4[(r6 << 5) + lane]);
    float4 t7 = h4_to_f4(xh4[(r7 << 5) + lane]);
    float4 t8 = h4_to_f4(xh4[(r8 << 5) + lane]);
    float4 t9 = h4_to_f4(xh4[(r9 << 5) + lane]);
    float4 tA = h4_to_f4(xh4[(rA << 5) + lane]);
    float4 tB = h4_to_f4(xh4[(rB << 5) + lane]);
    float4 tC = h4_to_f4(xh4[(rC << 5) + lane]);
    float4 tD = h4_to_f4(xh4[(rD << 5) + lane]);
    float4 tE = h4_to_f4(xh4[(rE << 5) + lane]);
    float4 tF = h4_to_f4(xh4[(rF << 5) + lane]);
    acc_add(acc, t0); acc_add(acc, t1); acc_add(acc, t2); acc_add(acc, t3);
    acc_add(acc, t4); acc_add(acc, t5); acc_add(acc, t6); acc_add(acc, t7);
    acc_add(acc, t8); acc_add(acc, t9); acc_add(acc, tA); acc_add(acc, tB);
    acc_add(acc, tC); acc_add(acc, tD); acc_add(acc, tE); acc_add(acc, tF);
  }
  if (j < end) {                              // exactly one 8-chunk remainder
    uint4 cw = *(const uint4*)&csr[j];
    int r0 = cw.x & 0xFFFF, r1 = cw.x >> 16;
    int r2 = cw.y & 0xFFFF, r3 = cw.y >> 16;
    int r4 = cw.z & 0xFFFF, r5 = cw.z >> 16;
    int r6 = cw.w & 0xFFFF, r7 = cw.w >> 16;
    float4 t0 = h4_to_f4(xh4[(r0 << 5) + lane]);
    float4 t1 = h4_to_f4(xh4[(r1 << 5) + lane]);
    float4 t2 = h4_to_f4(xh4[(r2 << 5) + lane]);
    float4 t3 = h4_to_f4(xh4[(r3 << 5) + lane]);
    float4 t4 = h4_to_f4(xh4[(r4 << 5) + lane]);
    float4 t5 = h4_to_f4(xh4[(r5 << 5) + lane]);
    float4 t6 = h4_to_f4(xh4[(r6 << 5) + lane]);
    float4 t7 = h4_to_f4(xh4[(r7 << 5) + lane]);
    acc_add(acc, t0); acc_add(acc, t1); acc_add(acc, t2); acc_add(acc, t3);
    acc_add(acc, t4); acc_add(acc, t5); acc_add(acc, t6); acc_add(acc, t7);
  }
  float d = dinv[node];
  union { uint2 u; __half2 h[2]; } p;
  p.h[0] = __halves2half2(__float2half_rn(d * acc.x), __float2half_rn(d * acc.y));
  p.h[1] = __halves2half2(__float2half_rn(d * acc.z), __float2half_rn(d * acc.w));
  aggh4[(node << 5) + lane] = p.u;
  if (lane < 7) aggh4[(node << 5) + 25 + lane] = make_uint2(0u, 0u);  // K-pad
}

// Layer-2 pull: 8 lanes x uint4 per node, 32 nodes/block, 16-edge unroll.
__global__ __launch_bounds__(256) void k_pull2(const int2* __restrict__ rowinfo,
                                               const unsigned short* __restrict__ csr,
                                               const uint4* __restrict__ th4,
                                               const float* __restrict__ dinv,
                                               const float4* __restrict__ b2_4,
                                               float4* __restrict__ out4, int n) {
  int g = threadIdx.x >> 3;
  int lane = threadIdx.x & 7;
  int node = blockIdx.x * 32 + g;
  if (node >= n) return;

  uint4 sv = th4[(node << 3) + lane];
  float4 acc0 = h4_to_f4(make_uint2(sv.x, sv.y));
  float4 acc1 = h4_to_f4(make_uint2(sv.z, sv.w));

  int2 ri = rowinfo[node];
  int beg = ri.x, end = ri.x + ri.y;
  int j = beg;
  for (; j + 16 <= end; j += 16) {
    uint4 cw0 = *(const uint4*)&csr[j];
    uint4 cw1 = *(const uint4*)&csr[j + 8];
    int r0 = cw0.x & 0xFFFF, r1 = cw0.x >> 16;
    int r2 = cw0.y & 0xFFFF, r3 = cw0.y >> 16;
    int r4 = cw0.z & 0xFFFF, r5 = cw0.z >> 16;
    int r6 = cw0.w & 0xFFFF, r7 = cw0.w >> 16;
    int r8 = cw1.x & 0xFFFF, r9 = cw1.x >> 16;
    int rA = cw1.y & 0xFFFF, rB = cw1.y >> 16;
    int rC = cw1.z & 0xFFFF, rD = cw1.z >> 16;
    int rE = cw1.w & 0xFFFF, rF = cw1.w >> 16;
    uint4 u0 = th4[(r0 << 3) + lane];
    uint4 u1 = th4[(r1 << 3) + lane];
    uint4 u2 = th4[(r2 << 3) + lane];
    uint4 u3 = th4[(r3 << 3) + lane];
    uint4 u4 = th4[(r4 << 3) + lane];
    uint4 u5 = th4[(r5 << 3) + lane];
    uint4 u6 = th4[(r6 << 3) + lane];
    uint4 u7 = th4[(r7 << 3) + lane];
    uint4 u8 = th4[(r8 << 3) + lane];
    uint4 u9 = th4[(r9 << 3) + lane];
    uint4 uA = th4[(rA << 3) + lane];
    uint4 uB = th4[(rB << 3) + lane];
    uint4 uC = th4[(rC << 3) + lane];
    uint4 uD = th4[(rD << 3) + lane];
    uint4 uE = th4[(rE << 3) + lane];
    uint4 uF = th4[(rF << 3) + lane];
    acc_add(acc0, h4_to_f4(make_uint2(u0.x, u0.y)));
    acc_add(acc1, h4_to_f4(make_uint2(u0.z, u0.w)));
    acc_add(acc0, h4_to_f4(make_uint2(u1.x, u1.y)));
    acc_add(acc1, h4_to_f4(make_uint2(u1.z, u1.w)));
    acc_add(acc0, h4_to_f4(make_uint2(u2.x, u2.y)));
    acc_add(acc1, h4_to_f4(make_uint2(u2.z, u2.w)));
    acc_add(acc0, h4_to_f4(make_uint2(u3.x, u3.y)));
    acc_add(acc1, h4_to_f4(make_uint2(u3.z, u3.w)));
    acc_add(acc0, h4_to_f4(make_uint2(u4.x, u4.y)));
    acc_add(acc1, h4_to_f4(make_uint2(u4.z, u4.w)));
    acc_add(acc0, h4_to_f4(make_uint2(u5.x, u5.y)));
    acc_add(acc1, h4_to_f4(make_uint2(u5.z, u5.w)));
    acc_add(acc0, h4_to_f4(make_uint2(u6.x, u6.y)));
    acc_add(acc1, h4_to_f4(make_uint2(u6.z, u6.w)));
    acc_add(acc0, h4_to_f4(make_uint2(u7.x, u7.y)));
    acc_add(acc1, h4_to_f4(make_uint2(u7.z, u7.w)));
    acc_add(acc0, h4_to_f4(make_uint2(u8.x, u8.y)));
    acc_add(acc1, h4_to_f4(make_uint2(u8.z, u8.w)));
    acc_add(acc0, h4_to_f4(make_uint2(u9.x, u9.y)));
    acc_add(acc1, h4_to_f4(make_uint2(u9.z, u9.w)));
    acc_add(acc0, h4_to_f4(make_uint2(uA.x, uA.y)));
    acc_add(acc1, h4_to_f4(make_uint2(uA.z, uA.w)));
    acc_add(acc0, h4_to_f4(make_uint2(uB.x, uB.y)));
    acc_add(acc1, h4_to_f4(make_uint2(uB.z, uB.w)));
    acc_add(acc0, h4_to_f4(make_uint2(uC.x, uC.y)));
    acc_add(acc1, h4_to_f4(make_uint2(uC.z, uC.w)));
    acc_add(acc0, h4_to_f4(make_uint2(uD.x, uD.y)));
    acc_add(acc1, h4_to_f4(make_uint2(uD.z, uD.w)));
    acc_add(acc0, h4_to_f4(make_uint2(uE.x, uE.y)));
    acc_add(acc1, h4_to_f4(make_uint2(uE.z, uE.w)));
    acc_add(acc0, h4_to_f4(make_uint2(uF.x, uF.y)));
    acc_add(acc1, h4_to_f4(make_uint2(uF.z, uF.w)));
  }
  if (j < end) {                              // exactly one 8-chunk remainder
    uint4 cw = *(const uint4*)&csr[j];
    int r0 = cw.x & 0xFFFF, r1 = cw.x >> 16;
    int r2 = cw.y & 0xFFFF, r3 = cw.y >> 16;
    int r4 = cw.z & 0xFFFF, r5 = cw.z >> 16;
    int r6 = cw.w & 0xFFFF, r7 = cw.w >> 16;
    uint4 u0 = th4[(r0 << 3) + lane];
    uint4 u1 = th4[(r1 << 3) + lane];
    uint4 u2 = th4[(r2 << 3) + lane];
    uint4 u3 = th4[(r3 << 3) + lane];
    uint4 u4 = th4[(r4 << 3) + lane];
    uint4 u5 = th4[(r5 << 3) + lane];
    uint4 u6 = th4[(r6 << 3) + lane];
    uint4 u7 = th4[(r7 << 3) + lane];
    acc_add(acc0, h4_to_f4(make_uint2(u0.x, u0.y)));
    acc_add(acc1, h4_to_f4(make_uint2(u0.z, u0.w)));
    acc_add(acc0, h4_to_f4(make_uint2(u1.x, u1.y)));
    acc_add(acc1, h4_to_f4(make_uint2(u1.z, u1.w)));
    acc_add(acc0, h4_to_f4(make_uint2(u2.x, u2.y)));
    acc_add(acc1, h4_to_f4(make_uint2(u2.z, u2.w)));
    acc_add(acc0, h4_to_f4(make_uint2(u3.x, u3.y)));
    acc_add(acc1, h4_to_f4(make_uint2(u3.z, u3.w)));
    acc_add(acc0, h4_to_f4(make_uint2(u4.x, u4.y)));
    acc_add(acc1, h4_to_f4(make_uint2(u4.z, u4.w)));
    acc_add(acc0, h4_to_f4(make_uint2(u5.x, u5.y)));
    acc_add(acc1, h4_to_f4(make_uint2(u5.z, u5.w)));
    acc_add(acc0, h4_to_f4(make_uint2(u6.x, u6.y)));
    acc_add(acc1, h4_to_f4(make_uint2(u6.z, u6.w)));
    acc_add(acc0, h4_to_f4(make_uint2(u7.x, u7.y)));
    acc_add(acc1, h4_to_f4(make_uint2(u7.z, u7.w)));
  }
  float d = dinv[node];
  float4 bb0 = b2_4[lane * 2], bb1 = b2_4[lane * 2 + 1];
  out4[(node << 4) + lane * 2]     = make_float4(d * acc0.x + bb0.x, d * acc0.y + bb0.y,
                                                 d * acc0.z + bb0.z, d * acc0.w + bb0.w);
  out4[(node << 4) + lane * 2 + 1] = make_float4(d * acc1.x + bb1.x, d * acc1.y + bb1.y,
                                                 d * acc1.z + bb1.z, d * acc1.w + bb1.w);
}

// ---------------------------------------------------------------------------
// Fused MFMA GEMM: per 16-row strip, h1 = relu(aggh@W1+b1) (swizzled LDS),
// thh = dinv*(h1@W2).
// ---------------------------------------------------------------------------
__global__ __launch_bounds__(256, 2) void k_gemmf(const _Float16* __restrict__ A,
                                                  const _Float16* __restrict__ Wt1,
                                                  const float* __restrict__ b1,
                                                  const _Float16* __restrict__ Wt2,
                                                  const float* __restrict__ dinv,
                                                  _Float16* __restrict__ thh, int n) {
  __shared__ __align__(16) _Float16 lds[4][16 * 128];
  const int wid = threadIdx.x >> 6;
  const int lane = threadIdx.x & 63;
  const int lr = lane & 15;
  const int lk = lane >> 4;
  _Float16* myl = lds[wid];

  half8 B1[8][4];
#pragma unroll
  for (int nt = 0; nt < 8; ++nt)
#pragma unroll
    for (int ks = 0; ks < 4; ++ks)
      B1[nt][ks] = *(const half8*)&Wt1[(nt * 16 + lr) * 128 + ks * 32 + lk * 8];
  float bs[8];
#pragma unroll
  for (int nt = 0; nt < 8; ++nt) bs[nt] = b1[nt * 16 + lr];

  const int nstrips = (n + 15) >> 4;
  for (int s = blockIdx.x * 4 + wid; s < nstrips; s += gridDim.x * 4) {
    const int arow = s * 16 + lr;
    half8 a[4];
#pragma unroll
    for (int ks = 0; ks < 4; ++ks)
      a[ks] = (arow < n) ? *(const half8*)&A[(size_t)arow * 128 + ks * 32 + lk * 8]
                         : half8{0, 0, 0, 0, 0, 0, 0, 0};
    f32x4 acc[8];
#pragma unroll
    for (int nt = 0; nt < 8; ++nt) acc[nt] = f32x4{0.f, 0.f, 0.f, 0.f};
#pragma unroll
    for (int ks = 0; ks < 4; ++ks)
#pragma unroll
      for (int nt = 0; nt < 8; ++nt)
        acc[nt] = __builtin_amdgcn_mfma_f32_16x16x32_f16(a[ks], B1[nt][ks], acc[nt], 0, 0, 0);

#pragma unroll
    for (int r = 0; r < 4; ++r) {
      int row = lk * 4 + r;
#pragma unroll
      for (int nt = 0; nt < 8; ++nt)
        myl[row * 128 + SWZ(row, nt * 16 + lr)] =
            (_Float16)fmaxf(acc[nt][r] + bs[nt], 0.f);
    }

    half8 B2[4][4];
#pragma unroll
    for (int nt = 0; nt < 4; ++nt)
#pragma unroll
      for (int ks = 0; ks < 4; ++ks)
        B2[nt][ks] = *(const half8*)&Wt2[(nt * 16 + lr) * 128 + ks * 32 + lk * 8];

    half8 a2[4];
#pragma unroll
    for (int ks = 0; ks < 4; ++ks)
      a2[ks] = *(const half8*)&myl[lr * 128 + SWZ(lr, ks * 32 + lk * 8)];

    f32x4 acc2[4];
#pragma unroll
    for (int nt = 0; nt < 4; ++nt) acc2[nt] = f32x4{0.f, 0.f, 0.f, 0.f};
#pragma unroll
    for (int ks = 0; ks < 4; ++ks)
#pragma unroll
      for (int nt = 0; nt < 4; ++nt)
        acc2[nt] = __builtin_amdgcn_mfma_f32_16x16x32_f16(a2[ks], B2[nt][ks], acc2[nt], 0, 0, 0);

    const int rb = s * 16 + lk * 4;
    float sc[4];
    if (rb + 3 < n) {
      const float4 dv = *(const float4*)&dinv[rb];
      sc[0] = dv.x; sc[1] = dv.y; sc[2] = dv.z; sc[3] = dv.w;
    } else {
#pragma unroll
      for (int r = 0; r < 4; ++r) sc[r] = (rb + r < n) ? dinv[rb + r] : 0.f;
    }
#pragma unroll
    for (int r = 0; r < 4; ++r) {
      const int orow = rb + r;
      if (orow < n) {
#pragma unroll
        for (int nt = 0; nt < 4; ++nt)
          thh[(size_t)orow * 64 + nt * 16 + lr] = (_Float16)(acc2[nt][r] * sc[r]);
      }
    }
  }
}

// ---------------------------------------------------------------------------
extern "C" void kernel_launch(void* const* d_in, const int* in_sizes, int n_in,
                              void* d_out, int out_size, void* d_ws, size_t ws_size,
                              hipStream_t stream) {
  const float* x  = (const float*)d_in[0];
  const void*  ei = d_in[1];
  const float* W1 = (const float*)d_in[2];
  const float* b1 = (const float*)d_in[3];
  const float* W2 = (const float*)d_in[4];
  const float* b2 = (const float*)d_in[5];
  float* out = (float*)d_out;

  const int n = in_sizes[0] / 100;   // 50000 (multiple of 16; n < 65536)
  const int E = in_sizes[1] / 2;     // 800000
  const int nbuk = DIV_UP(n, BUK_SIZE);  // 196

  // byte allocator, 16B-aligned
  char* ws = (char*)d_ws;
  size_t off = 0;
  auto alloc = [&](size_t bytes) { void* p = ws + off; off += (bytes + 15) & ~15ull; return p; };
  int*            bcur     = (int*)   alloc(MAXBUK * 4);
  float*          dinv     = (float*) alloc((size_t)n * 4);
  int2*           rowinfo  = (int2*)  alloc((size_t)n * 8);
  unsigned int*   recs     = (unsigned int*)alloc((size_t)nbuk * BUK_CAP * 4);
  unsigned short* csr      = (unsigned short*)alloc((size_t)nbuk * CSR_CAP * 2);
  _Float16*       xh       = (_Float16*)alloc((size_t)(n + 1) * 128 * 2);  // + zero row
  _Float16*       aggh     = (_Float16*)alloc((size_t)n * 128 * 2);        // K-padded
  _Float16*       thh      = (_Float16*)alloc((size_t)(n + 1) * 64 * 2);   // + zero row
  _Float16*       Wt1h     = (_Float16*)alloc(128 * 128 * 2);
  _Float16*       Wt2h     = (_Float16*)alloc(64 * 128 * 2);

  k_init<<<97, 256, 0, stream>>>(bcur, W1, W2, Wt1h, Wt2h);
  k_bucket<<<NBLK_BUCKET, 256, 0, stream>>>(ei, bcur, recs, E, nbuk);
  k_bdeg_fill<<<nbuk, 256, 0, stream>>>(bcur, recs, dinv, rowinfo, csr, n);

  const int total = (n + 1) * 32;
  k_convx<<<DIV_UP(total + 16, 256), 256, 0, stream>>>((const float4*)x, dinv,
      (uint2*)xh, (uint2*)thh, n, total);

  k_pull1<<<DIV_UP(n, 10), 256, 0, stream>>>(rowinfo, csr, (const uint2*)xh, dinv,
                                             (uint2*)aggh, n);
  const int nstrips = DIV_UP(n, 16);
  k_gemmf<<<DIV_UP(nstrips, 8), 256, 0, stream>>>(aggh, Wt1h, b1, Wt2h, dinv, thh, n);
  k_pull2<<<DIV_UP(n, 32), 256, 0, stream>>>(rowinfo, csr, (const uint4*)thh, dinv,
                                             (const float4*)b2, (float4*)out, n);
}